// Round 3
// baseline (923.666 us; speedup 1.0000x reference)
//
#include <hip/hip_runtime.h>
#include <stdint.h>

// B=2, T=2048, D=3584, N=16, KH=8, H=256, G=2, WINDOW=1024
// Inputs FLOAT32; compute bf16 MFMA; output FLOAT32.
// attn_mask unused: tril ∧ triu(1-W) ≡ t-1023 <= s <= t (diag always valid).

typedef short bf16x8 __attribute__((ext_vector_type(8)));   // 8 bf16 = 4 VGPRs
typedef float f32x4 __attribute__((ext_vector_type(4)));

#define MFMA16(a, b, c) __builtin_amdgcn_mfma_f32_16x16x32_bf16((a), (b), (c), 0, 0, 0)

__device__ __forceinline__ uint16_t f2bf(float f) {
  uint32_t u = __builtin_bit_cast(uint32_t, f);
  u += 0x7FFFu + ((u >> 16) & 1u);   // RNE
  return (uint16_t)(u >> 16);
}
__device__ __forceinline__ float bf2f(uint16_t u) {
  return __builtin_bit_cast(float, (uint32_t)u << 16);
}
// async global->LDS, 16B/lane; LDS dest must be wave-uniform base + lane*16.
__device__ __forceinline__ void async16(void* lds, const void* g) {
  __builtin_amdgcn_global_load_lds(
      (const __attribute__((address_space(1))) uint32_t*)g,
      (__attribute__((address_space(3))) uint32_t*)lds, 16, 0, 0);
}

// ---------------------------------------------------------------------------
// x f32 -> bf16 (row-major copy); 8 elems/thread
// ---------------------------------------------------------------------------
__global__ void convert_x(const float* __restrict__ x, uint16_t* __restrict__ xb) {
  size_t i = ((size_t)blockIdx.x * 256 + threadIdx.x) * 8;
  f32x4 a = *(const f32x4*)(x + i);
  f32x4 b = *(const f32x4*)(x + i + 4);
  bf16x8 r;
  r[0] = (short)f2bf(a[0]); r[1] = (short)f2bf(a[1]);
  r[2] = (short)f2bf(a[2]); r[3] = (short)f2bf(a[3]);
  r[4] = (short)f2bf(b[0]); r[5] = (short)f2bf(b[1]);
  r[6] = (short)f2bf(b[2]); r[7] = (short)f2bf(b[3]);
  *(bf16x8*)(xb + i) = r;
}

// ---------------------------------------------------------------------------
// Weight transposes (f32 in, bf16 out), B^T (n-major, k-contiguous) layout
// ---------------------------------------------------------------------------
__global__ void transpose_qkvw(const float* __restrict__ qw,
                               const float* __restrict__ kvw,
                               uint16_t* __restrict__ WqkvT) {
  __shared__ uint16_t tile[64][65];
  const int j0 = blockIdx.x * 64;
  const int d0 = blockIdx.y * 64;
  const int t = threadIdx.x;
  const int jl = t & 63;
  const int q4 = t >> 6;
  const int j = j0 + jl;
  const float* src;
  if (j0 < 4096) {
    src = qw + (size_t)(j >> 8) * 3584 * 256 + (j & 255);
  } else {
    int j2 = j - 4096;
    src = kvw + ((size_t)((j2 >> 11) * 8 + ((j2 >> 8) & 7)) * 3584) * 256 + (j2 & 255);
  }
#pragma unroll
  for (int r = 0; r < 16; ++r) {
    int dl = r * 4 + q4;
    tile[jl][dl] = f2bf(src[(size_t)(d0 + dl) * 256]);
  }
  __syncthreads();
#pragma unroll
  for (int r = 0; r < 16; ++r) {
    int jl2 = r * 4 + q4;
    WqkvT[(size_t)(j0 + jl2) * 3584 + d0 + jl] = tile[jl2][jl];
  }
}

// WoT[d][j] = o_w flat (4096 x 3584)[j][d], f32 -> bf16
__global__ void transpose_ow(const float* __restrict__ ow, uint16_t* __restrict__ WoT) {
  __shared__ uint16_t tile[64][65];
  const int d0 = blockIdx.x * 64;
  const int j0 = blockIdx.y * 64;
  const int t = threadIdx.x;
  const int c = t & 63;
  const int q4 = t >> 6;
#pragma unroll
  for (int r = 0; r < 16; ++r) {
    int jl = r * 4 + q4;
    tile[c][jl] = f2bf(ow[(size_t)(j0 + jl) * 3584 + d0 + c]);   // coalesced in d
  }
  __syncthreads();
#pragma unroll
  for (int r = 0; r < 16; ++r) {
    int dl = r * 4 + q4;
    WoT[(size_t)(d0 + dl) * 4096 + j0 + c] = tile[dl][c];        // coalesced in j
  }
}

// ---------------------------------------------------------------------------
// GEMM, 256x256-tile deep-pipelined schedule (unchanged from R1; verified):
//   512 threads = 8 waves (2 M x 4 N); BK=32; 4-slot LDS ring (128 KB);
//   global_load_lds w/ pre-swizzled source; counted vmcnt(8); setprio.
// EPI 0: epilogue routes cols to Q / K / V^T bf16 buffers.
// EPI 1: epilogue stores f32 to Oq.
// ---------------------------------------------------------------------------
template <int EPI>
__global__ __launch_bounds__(512, 2) void gemm256(
    const uint16_t* __restrict__ A, const uint16_t* __restrict__ Bt,
    int Kd, int Nc, int nbx,
    void* __restrict__ Oqv, uint16_t* __restrict__ Ok, uint16_t* __restrict__ Ov) {
  __shared__ uint16_t lds[4 * 16384];   // 128 KiB

  const int tid = threadIdx.x;
  const int lane = tid & 63;
  const int quad = lane >> 4;
  const int l15 = lane & 15;
  const int wave = tid >> 6;
  const int wm = wave & 1;        // M half (128 rows)
  const int wn = wave >> 1;       // N quarter (64 cols)

  // T1: XCD-aware bijective swizzle (requires nwg % 8 == 0; 512 and 224 both ok)
  const int nwg = gridDim.x;
  const int chunk = nwg >> 3;
  const int wg = blockIdx.x;
  const int swz = (wg & 7) * chunk + (wg >> 3);
  const int by = swz / nbx;
  const int bx = swz - by * nbx;
  const int m0 = by * 256;
  const int n0 = bx * 256;

  f32x4 acc[8][4];
#pragma unroll
  for (int i = 0; i < 8; ++i)
#pragma unroll
    for (int j = 0; j < 4; ++j) acc[i][j] = f32x4{0.f, 0.f, 0.f, 0.f};

  // Staging source pointers (pre-swizzled global chunk; LDS dest stays linear)
  const int srow = tid >> 2;              // 0..127
  const int sck = tid & 3;                // 16B chunk within 64B row
  const int gck0 = sck ^ ((srow >> 1) & 3);          // rows 0..127 and 128..255
  const int gck1 = sck ^ (((srow + 128) >> 1) & 3);  // share (row>>1)&3 parity
  const uint16_t* gA0 = A + (size_t)(m0 + srow) * Kd + gck0 * 8;
  const uint16_t* gA1 = A + (size_t)(m0 + srow + 128) * Kd + gck1 * 8;
  const uint16_t* gB0 = Bt + (size_t)(n0 + srow) * Kd + gck0 * 8;
  const uint16_t* gB1 = Bt + (size_t)(n0 + srow + 128) * Kd + gck1 * 8;

  const int T = Kd >> 5;                  // K tiles (112 or 128, both >= 3)

  // Prologue: stage tiles 0,1,2 into slots 0,1,2 (12 loads/thread)
#pragma unroll
  for (int pt = 0; pt < 3; ++pt) {
    uint16_t* sd = lds + pt * 16384;
    const int kt = pt * 32;
    async16(sd + tid * 8, gA0 + kt);
    async16(sd + 4096 + tid * 8, gA1 + kt);
    async16(sd + 8192 + tid * 8, gB0 + kt);
    async16(sd + 12288 + tid * 8, gB1 + kt);
  }
  asm volatile("s_waitcnt vmcnt(8)" ::: "memory");   // tile 0 landed
  __builtin_amdgcn_s_barrier();

  const int arow = wm * 128;
  const int brow = wn * 64;

  for (int t = 0; t < T; ++t) {
    const uint16_t* sA = lds + (t & 3) * 16384;
    const uint16_t* sB = sA + 8192;
    uint16_t* sd = lds + ((t + 3) & 3) * 16384;      // prefetch dest slot
    int ts = t + 3;
    if (ts >= T) ts = T - 1;                         // clamped source; never consumed
    const int ktS = ts * 32;

    // ---- phase 0: B frags (all 4) + A frags m-half 0; stage next A ----
    bf16x8 bfr[4], af[4];
#pragma unroll
    for (int fn = 0; fn < 4; ++fn) {
      const int r = brow + fn * 16 + l15;
      bfr[fn] = *(const bf16x8*)(sB + r * 32 + ((quad ^ ((r >> 1) & 3)) << 3));
    }
#pragma unroll
    for (int i = 0; i < 4; ++i) {
      const int r = arow + i * 16 + l15;
      af[i] = *(const bf16x8*)(sA + r * 32 + ((quad ^ ((r >> 1) & 3)) << 3));
    }
    async16(sd + tid * 8, gA0 + ktS);
    async16(sd + 4096 + tid * 8, gA1 + ktS);
    __builtin_amdgcn_s_barrier();
    __builtin_amdgcn_s_setprio(1);
#pragma unroll
    for (int i = 0; i < 4; ++i)
#pragma unroll
      for (int fn = 0; fn < 4; ++fn)
        acc[i][fn] = MFMA16(af[i], bfr[fn], acc[i][fn]);
    __builtin_amdgcn_s_setprio(0);
    __builtin_amdgcn_s_barrier();

    // ---- phase 1: A frags m-half 1 (B reused); stage next B; counted vmcnt ----
#pragma unroll
    for (int i = 0; i < 4; ++i) {
      const int r = arow + 64 + i * 16 + l15;
      af[i] = *(const bf16x8*)(sA + r * 32 + ((quad ^ ((r >> 1) & 3)) << 3));
    }
    async16(sd + 8192 + tid * 8, gB0 + ktS);
    async16(sd + 12288 + tid * 8, gB1 + ktS);
    asm volatile("s_waitcnt vmcnt(8)" ::: "memory");  // drains tile t+1; t+2/t+3 stay in flight
    __builtin_amdgcn_s_barrier();
    __builtin_amdgcn_s_setprio(1);
#pragma unroll
    for (int i = 0; i < 4; ++i)
#pragma unroll
      for (int fn = 0; fn < 4; ++fn)
        acc[4 + i][fn] = MFMA16(af[i], bfr[fn], acc[4 + i][fn]);
    __builtin_amdgcn_s_setprio(0);
    __builtin_amdgcn_s_barrier();
  }

  // Drain remaining LDS-DMA before wave exit (slots die with the workgroup).
  asm volatile("s_waitcnt vmcnt(0)" ::: "memory");

  // C layout per 16x16 frag: col = lane&15, row = quad*4 + reg (guide-verified)
  const int rowb = m0 + wm * 128;
  const int colb = n0 + wn * 64;
  if (EPI == 0) {
    if (n0 < 4096) {           // Q: (B*T, N*H)
      uint16_t* Oq = (uint16_t*)Oqv;
#pragma unroll
      for (int fm = 0; fm < 8; ++fm)
#pragma unroll
        for (int fn = 0; fn < 4; ++fn) {
          const int r0 = rowb + fm * 16 + quad * 4;
          const int c = colb + fn * 16 + l15;
#pragma unroll
          for (int reg = 0; reg < 4; ++reg)
            Oq[(size_t)(r0 + reg) * 4096 + c] = f2bf(acc[fm][fn][reg]);
        }
    } else if (n0 < 6144) {    // K: (B*T, KH*H)
#pragma unroll
      for (int fm = 0; fm < 8; ++fm)
#pragma unroll
        for (int fn = 0; fn < 4; ++fn) {
          const int r0 = rowb + fm * 16 + quad * 4;
          const int c = colb + fn * 16 + l15 - 4096;
#pragma unroll
          for (int reg = 0; reg < 4; ++reg)
            Ok[(size_t)(r0 + reg) * 2048 + c] = f2bf(acc[fm][fn][reg]);
        }
    } else {                   // V transposed: Vt[b][kvh][h][t]
#pragma unroll
      for (int fm = 0; fm < 8; ++fm)
#pragma unroll
        for (int fn = 0; fn < 4; ++fn) {
          const int r0 = rowb + fm * 16 + quad * 4;   // 4 consecutive t
          const int c2 = colb + fn * 16 + l15 - 6144;
          const int kvh = c2 >> 8, h = c2 & 255;
          const int bb = r0 >> 11, tt = r0 & 2047;
          ushort4 pk;
          pk.x = f2bf(acc[fm][fn][0]);
          pk.y = f2bf(acc[fm][fn][1]);
          pk.z = f2bf(acc[fm][fn][2]);
          pk.w = f2bf(acc[fm][fn][3]);
          *(ushort4*)(Ov + ((((size_t)bb * 8 + kvh) * 256 + h) * 2048 + tt)) = pk;
        }
    }
  } else {                     // f32 output
    float* Oq = (float*)Oqv;
#pragma unroll
    for (int fm = 0; fm < 8; ++fm)
#pragma unroll
      for (int fn = 0; fn < 4; ++fn) {
        const int r0 = rowb + fm * 16 + quad * 4;
        const int c = colb + fn * 16 + l15;
#pragma unroll
        for (int reg = 0; reg < 4; ++reg)
          Oq[(size_t)(r0 + reg) * Nc + c] = acc[fm][fn][reg];
      }
  }
}

// ---------------------------------------------------------------------------
// RoPE in place on Q (B,T,N,H) and K (B,T,KH,H) [bf16]; Q additionally * 0.0625
// ---------------------------------------------------------------------------
__global__ void rope_kernel(uint16_t* __restrict__ Qb, uint16_t* __restrict__ Kb,
                            const int* __restrict__ segpos) {
  const size_t QN = (size_t)2 * 2048 * 16 * 128;   // 8388608 Q pairs
  size_t idx = (size_t)blockIdx.x * 256 + threadIdx.x;
  uint16_t* buf;
  size_t base;
  int i, t, b;
  bool isQ = idx < QN;
  if (isQ) {
    i = (int)(idx & 127);
    int nn = (int)((idx >> 7) & 15);
    t = (int)((idx >> 11) & 2047);
    b = (int)(idx >> 22);
    base = ((size_t)((b * 2048 + t) * 16 + nn) << 8) + i;
    buf = Qb;
  } else {
    size_t x2 = idx - QN;
    i = (int)(x2 & 127);
    int kh = (int)((x2 >> 7) & 7);
    t = (int)((x2 >> 10) & 2047);
    b = (int)(x2 >> 21);
    base = ((size_t)((b * 2048 + t) * 8 + kh) << 8) + i;
    buf = Kb;
  }
  float pos = (float)segpos[b * 2048 + t];
  float inv = exp2f((float)i * (-13.287712379549449f / 128.f));  // 10000^(-i/128)
  float ang = pos * inv;
  float sn = sinf(ang), cs = cosf(ang);
  float x1 = bf2f(buf[base]);
  float x2v = bf2f(buf[base + 128]);
  float o1 = x1 * cs - x2v * sn;
  float o2 = x2v * cs + x1 * sn;
  if (isQ) { o1 *= 0.0625f; o2 *= 0.0625f; }
  buf[base] = f2bf(o1);
  buf[base + 128] = f2bf(o2);
}

// ---------------------------------------------------------------------------
// Flash attention v3: 32 q-rows/block, 4 waves = (2 heads x 2 row-halves).
//  - K tile staged via global_load_lds (swizzled; as v2, verified).
//  - Q hoisted to registers once (8x bf16x8).
//  - V read direct from global (L2-resident) but BATCHED into vf0[16]/vf1[16]
//    register arrays: vf0 issued before softmax (hidden under VALU), vf1
//    issued after softmax (hidden under PV batch 0 MFMAs). This is the T14
//    issue-early/use-late fix for v2's serialized per-MFMA V loads (VGPR=84
//    showed the compiler reused one reg pair -> 32 x ~200cy exposed/tile).
//  - Per tile: QK -> sync -> DMA next K -> vf0 -> softmax -> vf1 -> PV0 -> PV1 -> sync.
// ---------------------------------------------------------------------------
__device__ __forceinline__ void stage_k(uint16_t* Ks, const uint16_t* kge,
                                        const uint16_t* kgo, int tid, int s0) {
#pragma unroll
  for (int r = 0; r < 8; ++r) {
    const uint16_t* src = ((r & 1) ? kgo : kge) + (size_t)(s0 + r * 8) * 2048;
    async16(Ks + r * 2048 + tid * 8, src);
  }
}

__global__ __launch_bounds__(256, 2) void attn_kernel(
    const uint16_t* __restrict__ Qb, const uint16_t* __restrict__ Kb,
    const uint16_t* __restrict__ Vt, uint16_t* __restrict__ enc) {
  __shared__ uint16_t Ks[64 * 256];     // 32 KB K tile, chunk-swizzled
  __shared__ uint16_t Ps[4 * 16 * 72];  // 9 KB per-wave P (16 x 64, stride 72)
  const int tid = threadIdx.x;
  const int lane = tid & 63;
  const int wave = tid >> 6;
  const int quad = lane >> 4;
  const int l15 = lane & 15;

  // XCD swizzle: 1024 wgs; xcd i gets 128 consecutive swz = (b,kvh) in {2i,2i+1}
  const int bid = blockIdx.x;
  const int swz = (bid & 7) * 128 + (bid >> 3);
  const int qt0 = (swz & 63) * 32;
  const int y = swz >> 6;
  const int b = y >> 3;
  const int kvh = y & 7;
  const int g = wave & 1;
  const int wr = (wave >> 1) * 16;
  const int n = kvh * 2 + g;

  f32x4 oacc[16];
#pragma unroll
  for (int ht = 0; ht < 16; ++ht) oacc[ht] = f32x4{0.f, 0.f, 0.f, 0.f};
  float mrow[4], lrow[4];
#pragma unroll
  for (int r = 0; r < 4; ++r) { mrow[r] = -50.f; lrow[r] = 0.f; }

  // Q hoisted to registers: 16 rows (l15), head n, chunk quad + c*32
  const uint16_t* qp =
      Qb + ((size_t)((b * 2048 + qt0 + wr + l15) * 16 + n) << 8) + quad * 8;
  bf16x8 q[8];
#pragma unroll
  for (int c = 0; c < 8; ++c) q[c] = *(const bf16x8*)(qp + c * 32);

  // K staging pointers: row s at Kb + b*4194304 + kvh*256 + s*2048
  const int srow8 = tid >> 5;           // 0..7 (row within 8-row group)
  const int schunk = tid & 31;          // dest 16B chunk
  const uint16_t* kgb = Kb + (size_t)b * 4194304 + kvh * 256;
  const uint16_t* kge = kgb + srow8 * 2048 + ((schunk ^ srow8) << 3);
  const uint16_t* kgo = kgb + srow8 * 2048 + ((schunk ^ srow8 ^ 8) << 3);

  // V direct-global base: Vt[(b*8+kvh)][h][s]; this lane reads rows ht*16+l15
  const uint16_t* vgl = Vt + ((size_t)(b * 8 + kvh) << 19) +
                        (size_t)l15 * 2048 + quad * 8;

  int lo = qt0 - 1023;
  if (lo < 0) lo = 0;
  const int s0_start = (lo >> 6) << 6;

  stage_k(Ks, kge, kgo, tid, s0_start);
  __syncthreads();   // tile 0 visible (vmcnt 0 + barrier)

  for (int s0 = s0_start; s0 <= qt0; s0 += 64) {
    // ---- QK^T ----
    f32x4 sac[4];
#pragma unroll
    for (int j = 0; j < 4; ++j) sac[j] = f32x4{0.f, 0.f, 0.f, 0.f};
    __builtin_amdgcn_s_setprio(1);
#pragma unroll
    for (int c = 0; c < 8; ++c) {
#pragma unroll
      for (int j = 0; j < 4; ++j) {
        // stored: Ks[row][cd] = K[row][cd ^ (row&15)]; row&15 == l15 here
        bf16x8 kf = *(const bf16x8*)(Ks + (j * 16 + l15) * 256 +
                                     (((c * 4 + quad) ^ l15) << 3));
        sac[j] = MFMA16(q[c], kf, sac[j]);
      }
    }
    __builtin_amdgcn_s_setprio(0);
    __syncthreads();   // all waves' K reads retired -> safe to overwrite Ks
    if (s0 + 64 <= qt0) stage_k(Ks, kge, kgo, tid, s0 + 64);  // DMA under compute

    // ---- V batch 0 issued early: 16 independent loads, hidden under softmax ----
    bf16x8 vf0[16];
#pragma unroll
    for (int ht = 0; ht < 16; ++ht)
      vf0[ht] = *(const bf16x8*)(vgl + (size_t)(ht * 16) * 2048 + s0);

    // ---- softmax (rows quad*4+reg), online, defer-max THR=8 ----
#pragma unroll
    for (int reg = 0; reg < 4; ++reg) {
      const int t = qt0 + wr + quad * 4 + reg;
      float pv[4];
      float mx = -1e30f;
#pragma unroll
      for (int j = 0; j < 4; ++j) {
        int s = s0 + j * 16 + l15;
        float v = sac[j][reg];
        float e = __expf(v * 0.04f);                 // e^{2v/50}
        float scv = 50.f - 100.f / (e + 1.f);        // 50*tanh(v/50)
        bool valid = (s <= t) && (s + 1024 > t);
        v = valid ? scv : -1e30f;
        pv[j] = v;
        mx = fmaxf(mx, v);
      }
      mx = fmaxf(mx, __shfl_xor(mx, 1));
      mx = fmaxf(mx, __shfl_xor(mx, 2));
      mx = fmaxf(mx, __shfl_xor(mx, 4));
      mx = fmaxf(mx, __shfl_xor(mx, 8));
      float mold = mrow[reg];
      if (!__all(mx <= mold + 8.f)) {               // T13: rescale only on growth
        float mnew = fmaxf(mold, mx);
        float alpha = __expf(mold - mnew);
        lrow[reg] *= alpha;
#pragma unroll
        for (int ht = 0; ht < 16; ++ht) oacc[ht][reg] *= alpha;
        mrow[reg] = mnew;
        mold = mnew;
      }
      float rs = 0.f;
#pragma unroll
      for (int j = 0; j < 4; ++j) {
        float p = __expf(pv[j] - mold);              // bounded by e^8
        pv[j] = p;
        rs += p;
      }
      rs += __shfl_xor(rs, 1);
      rs += __shfl_xor(rs, 2);
      rs += __shfl_xor(rs, 4);
      rs += __shfl_xor(rs, 8);
      lrow[reg] += rs;
      const int r = quad * 4 + reg;
#pragma unroll
      for (int j = 0; j < 4; ++j)
        Ps[wave * 1152 + r * 72 + j * 16 + l15] = f2bf(pv[j]);
    }

    // ---- V batch 1 issued: hidden under PV batch 0 MFMAs ----
    bf16x8 vf1[16];
#pragma unroll
    for (int ht = 0; ht < 16; ++ht)
      vf1[ht] = *(const bf16x8*)(vgl + (size_t)(ht * 16) * 2048 + s0 + 32);

    // ---- PV: P from per-wave LDS, V from register batches ----
    bf16x8 pf0 = *(const bf16x8*)(Ps + wave * 1152 + l15 * 72 + quad * 8);
    __builtin_amdgcn_s_setprio(1);
#pragma unroll
    for (int ht = 0; ht < 16; ++ht)
      oacc[ht] = MFMA16(pf0, vf0[ht], oacc[ht]);
    __builtin_amdgcn_s_setprio(0);
    bf16x8 pf1 = *(const bf16x8*)(Ps + wave * 1152 + l15 * 72 + 32 + quad * 8);
    __builtin_amdgcn_s_setprio(1);
#pragma unroll
    for (int ht = 0; ht < 16; ++ht)
      oacc[ht] = MFMA16(pf1, vf1[ht], oacc[ht]);
    __builtin_amdgcn_s_setprio(0);
    __syncthreads();   // vmcnt(0): next K tile landed + all waves past PV
  }

#pragma unroll
  for (int reg = 0; reg < 4; ++reg) {
    float li = 1.f / lrow[reg];
    const int t = qt0 + wr + quad * 4 + reg;
    size_t base = ((size_t)((b * 2048 + t) * 16 + n) << 8) + l15;
#pragma unroll
    for (int ht = 0; ht < 16; ++ht)
      enc[base + ht * 16] = f2bf(oacc[ht][reg] * li);
  }
}

// ---------------------------------------------------------------------------
extern "C" void kernel_launch(void* const* d_in, const int* in_sizes, int n_in,
                              void* d_out, int out_size, void* d_ws, size_t ws_size,
                              hipStream_t stream) {
  const float* x = (const float*)d_in[0];
  const int* segpos = (const int*)d_in[1];
  // d_in[2] = attn_mask — implied by window; unused
  const float* qw = (const float*)d_in[3];
  const float* kvw = (const float*)d_in[4];
  const float* ow = (const float*)d_in[5];
  float* out = (float*)d_out;

  uint16_t* ws = (uint16_t*)d_ws;
  uint16_t* WqkvT = ws;                              // 29,360,128 elems
  uint16_t* enc = ws;                                // aliases WqkvT (dead after gemm<0>)
  uint16_t* xb = ws + (size_t)29360128;              // 14,680,064 (aliases WoT; dead after gemm<0>)
  uint16_t* WoT = ws + (size_t)29360128;             // 14,680,064 (written after attn)
  uint16_t* Qb = ws + (size_t)44040192;              // 16,777,216
  uint16_t* Kb = ws + (size_t)60817408;              // 8,388,608
  uint16_t* Vt = ws + (size_t)69206016;              // 8,388,608  (total ~155 MB)

  convert_x<<<7168, 256, 0, stream>>>(x, xb);
  transpose_qkvw<<<dim3(128, 56), 256, 0, stream>>>(qw, kvw, WqkvT);
  // 256x256 tiles: QKV = (4096 x 8192) -> 16 x 32 = 512 wgs; O = (4096 x 3584) -> 16 x 14 = 224 wgs
  gemm256<0><<<dim3(512), dim3(512), 0, stream>>>(xb, WqkvT, 3584, 8192, 32, Qb, Kb, Vt);
  rope_kernel<<<49152, 256, 0, stream>>>(Qb, Kb, segpos);
  attn_kernel<<<dim3(1024), 256, 0, stream>>>(Qb, Kb, Vt, enc);
  transpose_ow<<<dim3(56, 64), 256, 0, stream>>>(ow, WoT);   // xb dead; reuse region
  gemm256<1><<<dim3(224), dim3(512), 0, stream>>>(enc, WoT, 4096, 3584, 14, out, nullptr, nullptr);
}

// Round 4
// 751.194 us; speedup vs baseline: 1.2296x; 1.2296x over previous
//
#include <hip/hip_runtime.h>
#include <stdint.h>

// B=2, T=2048, D=3584, N=16, KH=8, H=256, G=2, WINDOW=1024
// Inputs FLOAT32; compute bf16 MFMA; output FLOAT32.
// attn_mask unused: tril ∧ triu(1-W) ≡ t-1023 <= s <= t (diag always valid).

typedef short bf16x8 __attribute__((ext_vector_type(8)));   // 8 bf16 = 4 VGPRs
typedef float f32x4 __attribute__((ext_vector_type(4)));

#define MFMA16(a, b, c) __builtin_amdgcn_mfma_f32_16x16x32_bf16((a), (b), (c), 0, 0, 0)

__device__ __forceinline__ uint16_t f2bf(float f) {
  uint32_t u = __builtin_bit_cast(uint32_t, f);
  u += 0x7FFFu + ((u >> 16) & 1u);   // RNE
  return (uint16_t)(u >> 16);
}
__device__ __forceinline__ float bf2f(uint16_t u) {
  return __builtin_bit_cast(float, (uint32_t)u << 16);
}
// async global->LDS, 16B/lane; LDS dest must be wave-uniform base + lane*16.
__device__ __forceinline__ void async16(void* lds, const void* g) {
  __builtin_amdgcn_global_load_lds(
      (const __attribute__((address_space(1))) uint32_t*)g,
      (__attribute__((address_space(3))) uint32_t*)lds, 16, 0, 0);
}

// ---------------------------------------------------------------------------
// x f32 -> bf16 (row-major copy); 8 elems/thread
// ---------------------------------------------------------------------------
__global__ void convert_x(const float* __restrict__ x, uint16_t* __restrict__ xb) {
  size_t i = ((size_t)blockIdx.x * 256 + threadIdx.x) * 8;
  f32x4 a = *(const f32x4*)(x + i);
  f32x4 b = *(const f32x4*)(x + i + 4);
  bf16x8 r;
  r[0] = (short)f2bf(a[0]); r[1] = (short)f2bf(a[1]);
  r[2] = (short)f2bf(a[2]); r[3] = (short)f2bf(a[3]);
  r[4] = (short)f2bf(b[0]); r[5] = (short)f2bf(b[1]);
  r[6] = (short)f2bf(b[2]); r[7] = (short)f2bf(b[3]);
  *(bf16x8*)(xb + i) = r;
}

// ---------------------------------------------------------------------------
// Weight transposes (f32 in, bf16 out), B^T (n-major, k-contiguous) layout
// ---------------------------------------------------------------------------
__global__ void transpose_qkvw(const float* __restrict__ qw,
                               const float* __restrict__ kvw,
                               uint16_t* __restrict__ WqkvT) {
  __shared__ uint16_t tile[64][65];
  const int j0 = blockIdx.x * 64;
  const int d0 = blockIdx.y * 64;
  const int t = threadIdx.x;
  const int jl = t & 63;
  const int q4 = t >> 6;
  const int j = j0 + jl;
  const float* src;
  if (j0 < 4096) {
    src = qw + (size_t)(j >> 8) * 3584 * 256 + (j & 255);
  } else {
    int j2 = j - 4096;
    src = kvw + ((size_t)((j2 >> 11) * 8 + ((j2 >> 8) & 7)) * 3584) * 256 + (j2 & 255);
  }
#pragma unroll
  for (int r = 0; r < 16; ++r) {
    int dl = r * 4 + q4;
    tile[jl][dl] = f2bf(src[(size_t)(d0 + dl) * 256]);
  }
  __syncthreads();
#pragma unroll
  for (int r = 0; r < 16; ++r) {
    int jl2 = r * 4 + q4;
    WqkvT[(size_t)(j0 + jl2) * 3584 + d0 + jl] = tile[jl2][jl];
  }
}

// WoT[d][j] = o_w flat (4096 x 3584)[j][d], f32 -> bf16
__global__ void transpose_ow(const float* __restrict__ ow, uint16_t* __restrict__ WoT) {
  __shared__ uint16_t tile[64][65];
  const int d0 = blockIdx.x * 64;
  const int j0 = blockIdx.y * 64;
  const int t = threadIdx.x;
  const int c = t & 63;
  const int q4 = t >> 6;
#pragma unroll
  for (int r = 0; r < 16; ++r) {
    int jl = r * 4 + q4;
    tile[c][jl] = f2bf(ow[(size_t)(j0 + jl) * 3584 + d0 + c]);   // coalesced in d
  }
  __syncthreads();
#pragma unroll
  for (int r = 0; r < 16; ++r) {
    int dl = r * 4 + q4;
    WoT[(size_t)(d0 + dl) * 4096 + j0 + c] = tile[dl][c];        // coalesced in j
  }
}

// ---------------------------------------------------------------------------
// GEMM, 256x256-tile deep-pipelined schedule (unchanged from R1; verified):
//   512 threads = 8 waves (2 M x 4 N); BK=32; 4-slot LDS ring (128 KB);
//   global_load_lds w/ pre-swizzled source; counted vmcnt(8); setprio.
// EPI 0: epilogue routes cols to Q / K / V^T bf16 buffers.
// EPI 1: epilogue stores f32 to Oq.
// ---------------------------------------------------------------------------
template <int EPI>
__global__ __launch_bounds__(512, 2) void gemm256(
    const uint16_t* __restrict__ A, const uint16_t* __restrict__ Bt,
    int Kd, int Nc, int nbx,
    void* __restrict__ Oqv, uint16_t* __restrict__ Ok, uint16_t* __restrict__ Ov) {
  __shared__ uint16_t lds[4 * 16384];   // 128 KiB

  const int tid = threadIdx.x;
  const int lane = tid & 63;
  const int quad = lane >> 4;
  const int l15 = lane & 15;
  const int wave = tid >> 6;
  const int wm = wave & 1;        // M half (128 rows)
  const int wn = wave >> 1;       // N quarter (64 cols)

  // T1: XCD-aware bijective swizzle (requires nwg % 8 == 0; 512 and 224 both ok)
  const int nwg = gridDim.x;
  const int chunk = nwg >> 3;
  const int wg = blockIdx.x;
  const int swz = (wg & 7) * chunk + (wg >> 3);
  const int by = swz / nbx;
  const int bx = swz - by * nbx;
  const int m0 = by * 256;
  const int n0 = bx * 256;

  f32x4 acc[8][4];
#pragma unroll
  for (int i = 0; i < 8; ++i)
#pragma unroll
    for (int j = 0; j < 4; ++j) acc[i][j] = f32x4{0.f, 0.f, 0.f, 0.f};

  // Staging source pointers (pre-swizzled global chunk; LDS dest stays linear)
  const int srow = tid >> 2;              // 0..127
  const int sck = tid & 3;                // 16B chunk within 64B row
  const int gck0 = sck ^ ((srow >> 1) & 3);          // rows 0..127 and 128..255
  const int gck1 = sck ^ (((srow + 128) >> 1) & 3);  // share (row>>1)&3 parity
  const uint16_t* gA0 = A + (size_t)(m0 + srow) * Kd + gck0 * 8;
  const uint16_t* gA1 = A + (size_t)(m0 + srow + 128) * Kd + gck1 * 8;
  const uint16_t* gB0 = Bt + (size_t)(n0 + srow) * Kd + gck0 * 8;
  const uint16_t* gB1 = Bt + (size_t)(n0 + srow + 128) * Kd + gck1 * 8;

  const int T = Kd >> 5;                  // K tiles (112 or 128, both >= 3)

  // Prologue: stage tiles 0,1,2 into slots 0,1,2 (12 loads/thread)
#pragma unroll
  for (int pt = 0; pt < 3; ++pt) {
    uint16_t* sd = lds + pt * 16384;
    const int kt = pt * 32;
    async16(sd + tid * 8, gA0 + kt);
    async16(sd + 4096 + tid * 8, gA1 + kt);
    async16(sd + 8192 + tid * 8, gB0 + kt);
    async16(sd + 12288 + tid * 8, gB1 + kt);
  }
  asm volatile("s_waitcnt vmcnt(8)" ::: "memory");   // tile 0 landed
  __builtin_amdgcn_s_barrier();

  const int arow = wm * 128;
  const int brow = wn * 64;

  for (int t = 0; t < T; ++t) {
    const uint16_t* sA = lds + (t & 3) * 16384;
    const uint16_t* sB = sA + 8192;
    uint16_t* sd = lds + ((t + 3) & 3) * 16384;      // prefetch dest slot
    int ts = t + 3;
    if (ts >= T) ts = T - 1;                         // clamped source; never consumed
    const int ktS = ts * 32;

    // ---- phase 0: B frags (all 4) + A frags m-half 0; stage next A ----
    bf16x8 bfr[4], af[4];
#pragma unroll
    for (int fn = 0; fn < 4; ++fn) {
      const int r = brow + fn * 16 + l15;
      bfr[fn] = *(const bf16x8*)(sB + r * 32 + ((quad ^ ((r >> 1) & 3)) << 3));
    }
#pragma unroll
    for (int i = 0; i < 4; ++i) {
      const int r = arow + i * 16 + l15;
      af[i] = *(const bf16x8*)(sA + r * 32 + ((quad ^ ((r >> 1) & 3)) << 3));
    }
    async16(sd + tid * 8, gA0 + ktS);
    async16(sd + 4096 + tid * 8, gA1 + ktS);
    __builtin_amdgcn_s_barrier();
    __builtin_amdgcn_s_setprio(1);
#pragma unroll
    for (int i = 0; i < 4; ++i)
#pragma unroll
      for (int fn = 0; fn < 4; ++fn)
        acc[i][fn] = MFMA16(af[i], bfr[fn], acc[i][fn]);
    __builtin_amdgcn_s_setprio(0);
    __builtin_amdgcn_s_barrier();

    // ---- phase 1: A frags m-half 1 (B reused); stage next B; counted vmcnt ----
#pragma unroll
    for (int i = 0; i < 4; ++i) {
      const int r = arow + 64 + i * 16 + l15;
      af[i] = *(const bf16x8*)(sA + r * 32 + ((quad ^ ((r >> 1) & 3)) << 3));
    }
    async16(sd + 8192 + tid * 8, gB0 + ktS);
    async16(sd + 12288 + tid * 8, gB1 + ktS);
    asm volatile("s_waitcnt vmcnt(8)" ::: "memory");  // drains tile t+1; t+2/t+3 stay in flight
    __builtin_amdgcn_s_barrier();
    __builtin_amdgcn_s_setprio(1);
#pragma unroll
    for (int i = 0; i < 4; ++i)
#pragma unroll
      for (int fn = 0; fn < 4; ++fn)
        acc[4 + i][fn] = MFMA16(af[i], bfr[fn], acc[4 + i][fn]);
    __builtin_amdgcn_s_setprio(0);
    __builtin_amdgcn_s_barrier();
  }

  // Drain remaining LDS-DMA before wave exit (slots die with the workgroup).
  asm volatile("s_waitcnt vmcnt(0)" ::: "memory");

  // C layout per 16x16 frag: col = lane&15, row = quad*4 + reg (guide-verified)
  const int rowb = m0 + wm * 128;
  const int colb = n0 + wn * 64;
  if (EPI == 0) {
    if (n0 < 4096) {           // Q: (B*T, N*H)
      uint16_t* Oq = (uint16_t*)Oqv;
#pragma unroll
      for (int fm = 0; fm < 8; ++fm)
#pragma unroll
        for (int fn = 0; fn < 4; ++fn) {
          const int r0 = rowb + fm * 16 + quad * 4;
          const int c = colb + fn * 16 + l15;
#pragma unroll
          for (int reg = 0; reg < 4; ++reg)
            Oq[(size_t)(r0 + reg) * 4096 + c] = f2bf(acc[fm][fn][reg]);
        }
    } else if (n0 < 6144) {    // K: (B*T, KH*H)
#pragma unroll
      for (int fm = 0; fm < 8; ++fm)
#pragma unroll
        for (int fn = 0; fn < 4; ++fn) {
          const int r0 = rowb + fm * 16 + quad * 4;
          const int c = colb + fn * 16 + l15 - 4096;
#pragma unroll
          for (int reg = 0; reg < 4; ++reg)
            Ok[(size_t)(r0 + reg) * 2048 + c] = f2bf(acc[fm][fn][reg]);
        }
    } else {                   // V transposed: Vt[b][kvh][h][t]
#pragma unroll
      for (int fm = 0; fm < 8; ++fm)
#pragma unroll
        for (int fn = 0; fn < 4; ++fn) {
          const int r0 = rowb + fm * 16 + quad * 4;   // 4 consecutive t
          const int c2 = colb + fn * 16 + l15 - 6144;
          const int kvh = c2 >> 8, h = c2 & 255;
          const int bb = r0 >> 11, tt = r0 & 2047;
          ushort4 pk;
          pk.x = f2bf(acc[fm][fn][0]);
          pk.y = f2bf(acc[fm][fn][1]);
          pk.z = f2bf(acc[fm][fn][2]);
          pk.w = f2bf(acc[fm][fn][3]);
          *(ushort4*)(Ov + ((((size_t)bb * 8 + kvh) * 256 + h) * 2048 + tt)) = pk;
        }
    }
  } else {                     // f32 output
    float* Oq = (float*)Oqv;
#pragma unroll
    for (int fm = 0; fm < 8; ++fm)
#pragma unroll
      for (int fn = 0; fn < 4; ++fn) {
        const int r0 = rowb + fm * 16 + quad * 4;
        const int c = colb + fn * 16 + l15;
#pragma unroll
        for (int reg = 0; reg < 4; ++reg)
          Oq[(size_t)(r0 + reg) * Nc + c] = acc[fm][fn][reg];
      }
  }
}

// ---------------------------------------------------------------------------
// RoPE in place on Q (B,T,N,H) and K (B,T,KH,H) [bf16]; Q additionally * 0.0625
// ---------------------------------------------------------------------------
__global__ void rope_kernel(uint16_t* __restrict__ Qb, uint16_t* __restrict__ Kb,
                            const int* __restrict__ segpos) {
  const size_t QN = (size_t)2 * 2048 * 16 * 128;   // 8388608 Q pairs
  size_t idx = (size_t)blockIdx.x * 256 + threadIdx.x;
  uint16_t* buf;
  size_t base;
  int i, t, b;
  bool isQ = idx < QN;
  if (isQ) {
    i = (int)(idx & 127);
    int nn = (int)((idx >> 7) & 15);
    t = (int)((idx >> 11) & 2047);
    b = (int)(idx >> 22);
    base = ((size_t)((b * 2048 + t) * 16 + nn) << 8) + i;
    buf = Qb;
  } else {
    size_t x2 = idx - QN;
    i = (int)(x2 & 127);
    int kh = (int)((x2 >> 7) & 7);
    t = (int)((x2 >> 10) & 2047);
    b = (int)(x2 >> 21);
    base = ((size_t)((b * 2048 + t) * 8 + kh) << 8) + i;
    buf = Kb;
  }
  float pos = (float)segpos[b * 2048 + t];
  float inv = exp2f((float)i * (-13.287712379549449f / 128.f));  // 10000^(-i/128)
  float ang = pos * inv;
  float sn = sinf(ang), cs = cosf(ang);
  float x1 = bf2f(buf[base]);
  float x2v = bf2f(buf[base + 128]);
  float o1 = x1 * cs - x2v * sn;
  float o2 = x2v * cs + x1 * sn;
  if (isQ) { o1 *= 0.0625f; o2 *= 0.0625f; }
  buf[base] = f2bf(o1);
  buf[base + 128] = f2bf(o2);
}

// ---------------------------------------------------------------------------
// Flash attention v4: 64 q-rows/block, 512 threads = 8 waves
//   (4 row-groups x 2 heads). Double-buffered K AND V tiles staged entirely
//   by the LDS-DMA engine (global_load_lds, zero staging VGPRs -- v3's
//   register V batches spilled to scratch: VGPR=128 + WRITE_SIZE 3x).
//   Tile t+1's 8 DMA issues go out at the TOP of iter t and land during the
//   ~2000cy compute phase; ONE __syncthreads per tile flips buffers.
//   K LDS [64][256] chunk-swizzled c^(row&15); V LDS [256][64] chunk-swizzled
//   c^(h&7); both via pre-swizzled global source + same XOR on read.
// ---------------------------------------------------------------------------
__global__ __launch_bounds__(512, 2) void attn_kernel(
    const uint16_t* __restrict__ Qb, const uint16_t* __restrict__ Kb,
    const uint16_t* __restrict__ Vt, uint16_t* __restrict__ enc) {
  __shared__ uint16_t Ks[2][64 * 256];   // 2 x 32 KB
  __shared__ uint16_t Vs[2][256 * 64];   // 2 x 32 KB
  __shared__ uint16_t Ps[8 * 16 * 72];   // 18 KB per-wave P (16 x 64, stride 72)
  const int tid = threadIdx.x;
  const int lane = tid & 63;
  const int wave = tid >> 6;
  const int quad = lane >> 4;
  const int l15 = lane & 15;

  // XCD swizzle: 512 wgs; each XCD gets 64 consecutive swz = 2 (b,kvh) groups
  const int bid = blockIdx.x;
  const int swz = (bid & 7) * 64 + (bid >> 3);
  const int qt0 = (swz & 31) * 64;
  const int y = swz >> 5;          // 0..15
  const int b = y >> 3;
  const int kvh = y & 7;
  const int g = wave & 1;
  const int wr = (wave >> 1) * 16; // row group: 0,16,32,48
  const int n = kvh * 2 + g;

  f32x4 oacc[16];
#pragma unroll
  for (int ht = 0; ht < 16; ++ht) oacc[ht] = f32x4{0.f, 0.f, 0.f, 0.f};
  float mrow[4], lrow[4];
#pragma unroll
  for (int r = 0; r < 4; ++r) { mrow[r] = -50.f; lrow[r] = 0.f; }

  // Q hoisted to registers: rows qt0+wr+l15, head n, chunk quad + c*32
  const uint16_t* qptr =
      Qb + ((size_t)((b * 2048 + qt0 + wr + l15) * 16 + n) << 8) + quad * 8;
  bf16x8 q[8];
#pragma unroll
  for (int c = 0; c < 8; ++c) q[c] = *(const bf16x8*)(qptr + c * 32);

  // K staging: 4 issues, rows r*16 + (tid>>5), dest chunk tid&31,
  // source chunk (tid&31)^(row&15); row&15 == tid>>5 (r*16 doesn't affect).
  const int krw = tid >> 5;            // 0..15
  const uint16_t* kg0 = Kb + (size_t)b * 4194304 + kvh * 256 +
                        (size_t)krw * 2048 + (((tid & 31) ^ krw) << 3);
  // V staging: 4 issues, rows h = r*64 + (tid>>3), dest chunk tid&7,
  // source chunk (tid&7)^(h&7); h&7 == (tid>>3)&7.
  const int vrw = tid >> 3;            // 0..63
  const uint16_t* vg0 = Vt + ((size_t)(b * 8 + kvh) << 19) +
                        (size_t)vrw * 2048 + (((tid & 7) ^ (vrw & 7)) << 3);

  int lo = qt0 - 1023;
  if (lo < 0) lo = 0;
  const int s0_start = (lo >> 6) << 6;

  // Prologue: stage tile 0 into buffer 0
#pragma unroll
  for (int r = 0; r < 4; ++r)
    async16(&Ks[0][r * 4096 + tid * 8], kg0 + (size_t)(s0_start + r * 16) * 2048);
#pragma unroll
  for (int r = 0; r < 4; ++r)
    async16(&Vs[0][r * 4096 + tid * 8], vg0 + (size_t)r * 131072 + s0_start);
  __syncthreads();   // vmcnt(0)+barrier: tile 0 visible

  int cur = 0;
  for (int s0 = s0_start; s0 <= qt0; s0 += 64, cur ^= 1) {
    // ---- issue next tile's DMA (lands during this tile's compute) ----
    if (s0 + 64 <= qt0) {
      uint16_t* kd = Ks[cur ^ 1];
      uint16_t* vd = Vs[cur ^ 1];
#pragma unroll
      for (int r = 0; r < 4; ++r)
        async16(kd + r * 4096 + tid * 8, kg0 + (size_t)(s0 + 64 + r * 16) * 2048);
#pragma unroll
      for (int r = 0; r < 4; ++r)
        async16(vd + r * 4096 + tid * 8, vg0 + (size_t)r * 131072 + (s0 + 64));
    }
    const uint16_t* ksb = Ks[cur];
    const uint16_t* vsb = Vs[cur];

    // ---- QK^T ----
    f32x4 sac[4];
#pragma unroll
    for (int j = 0; j < 4; ++j) sac[j] = f32x4{0.f, 0.f, 0.f, 0.f};
    __builtin_amdgcn_s_setprio(1);
#pragma unroll
    for (int c = 0; c < 8; ++c) {
#pragma unroll
      for (int j = 0; j < 4; ++j) {
        // stored: Ks[row][cd] = K[row][cd ^ (row&15)]; row&15 == l15 here
        bf16x8 kf = *(const bf16x8*)(ksb + (j * 16 + l15) * 256 +
                                     (((c * 4 + quad) ^ l15) << 3));
        sac[j] = MFMA16(q[c], kf, sac[j]);
      }
    }
    __builtin_amdgcn_s_setprio(0);

    // ---- softmax (rows quad*4+reg), online, defer-max THR=8 ----
#pragma unroll
    for (int reg = 0; reg < 4; ++reg) {
      const int t = qt0 + wr + quad * 4 + reg;
      float pv[4];
      float mx = -1e30f;
#pragma unroll
      for (int j = 0; j < 4; ++j) {
        int s = s0 + j * 16 + l15;
        float v = sac[j][reg];
        float e = __expf(v * 0.04f);                 // e^{2v/50}
        float scv = 50.f - 100.f / (e + 1.f);        // 50*tanh(v/50)
        bool valid = (s <= t) && (s + 1024 > t);
        v = valid ? scv : -1e30f;
        pv[j] = v;
        mx = fmaxf(mx, v);
      }
      mx = fmaxf(mx, __shfl_xor(mx, 1));
      mx = fmaxf(mx, __shfl_xor(mx, 2));
      mx = fmaxf(mx, __shfl_xor(mx, 4));
      mx = fmaxf(mx, __shfl_xor(mx, 8));
      float mold = mrow[reg];
      if (!__all(mx <= mold + 8.f)) {               // T13: rescale only on growth
        float mnew = fmaxf(mold, mx);
        float alpha = __expf(mold - mnew);
        lrow[reg] *= alpha;
#pragma unroll
        for (int ht = 0; ht < 16; ++ht) oacc[ht][reg] *= alpha;
        mrow[reg] = mnew;
        mold = mnew;
      }
      float rs = 0.f;
#pragma unroll
      for (int j = 0; j < 4; ++j) {
        float p = __expf(pv[j] - mold);              // bounded by e^8
        pv[j] = p;
        rs += p;
      }
      rs += __shfl_xor(rs, 1);
      rs += __shfl_xor(rs, 2);
      rs += __shfl_xor(rs, 4);
      rs += __shfl_xor(rs, 8);
      lrow[reg] += rs;
      const int r = quad * 4 + reg;
#pragma unroll
      for (int j = 0; j < 4; ++j)
        Ps[wave * 1152 + r * 72 + j * 16 + l15] = f2bf(pv[j]);
    }

    // ---- PV: P from own wave's LDS region, V from swizzled LDS ----
#pragma unroll
    for (int c2 = 0; c2 < 2; ++c2) {
      const int lch = c2 * 4 + quad;
      bf16x8 pf = *(const bf16x8*)(Ps + wave * 1152 + l15 * 72 + lch * 8);
      __builtin_amdgcn_s_setprio(1);
#pragma unroll
      for (int ht = 0; ht < 16; ++ht) {
        // stored: Vs[h][cd] = V[h][cd ^ (h&7)]; h&7 == l15&7 here
        bf16x8 vf = *(const bf16x8*)(vsb + (ht * 16 + l15) * 64 +
                                     ((lch ^ (l15 & 7)) << 3));
        oacc[ht] = MFMA16(pf, vf, oacc[ht]);
      }
      __builtin_amdgcn_s_setprio(0);
    }
    __syncthreads();   // vmcnt(0)+barrier: next tile landed; all reads retired
  }

#pragma unroll
  for (int reg = 0; reg < 4; ++reg) {
    float li = 1.f / lrow[reg];
    const int t = qt0 + wr + quad * 4 + reg;
    size_t base = ((size_t)((b * 2048 + t) * 16 + n) << 8) + l15;
#pragma unroll
    for (int ht = 0; ht < 16; ++ht)
      enc[base + ht * 16] = f2bf(oacc[ht][reg] * li);
  }
}

// ---------------------------------------------------------------------------
extern "C" void kernel_launch(void* const* d_in, const int* in_sizes, int n_in,
                              void* d_out, int out_size, void* d_ws, size_t ws_size,
                              hipStream_t stream) {
  const float* x = (const float*)d_in[0];
  const int* segpos = (const int*)d_in[1];
  // d_in[2] = attn_mask — implied by window; unused
  const float* qw = (const float*)d_in[3];
  const float* kvw = (const float*)d_in[4];
  const float* ow = (const float*)d_in[5];
  float* out = (float*)d_out;

  uint16_t* ws = (uint16_t*)d_ws;
  uint16_t* WqkvT = ws;                              // 29,360,128 elems
  uint16_t* enc = ws;                                // aliases WqkvT (dead after gemm<0>)
  uint16_t* xb = ws + (size_t)29360128;              // 14,680,064 (aliases WoT; dead after gemm<0>)
  uint16_t* WoT = ws + (size_t)29360128;             // 14,680,064 (written after attn)
  uint16_t* Qb = ws + (size_t)44040192;              // 16,777,216
  uint16_t* Kb = ws + (size_t)60817408;              // 8,388,608
  uint16_t* Vt = ws + (size_t)69206016;              // 8,388,608  (total ~155 MB)

  convert_x<<<7168, 256, 0, stream>>>(x, xb);
  transpose_qkvw<<<dim3(128, 56), 256, 0, stream>>>(qw, kvw, WqkvT);
  // 256x256 tiles: QKV = (4096 x 8192) -> 16 x 32 = 512 wgs; O = (4096 x 3584) -> 16 x 14 = 224 wgs
  gemm256<0><<<dim3(512), dim3(512), 0, stream>>>(xb, WqkvT, 3584, 8192, 32, Qb, Kb, Vt);
  rope_kernel<<<49152, 256, 0, stream>>>(Qb, Kb, segpos);
  attn_kernel<<<dim3(512), dim3(512), 0, stream>>>(Qb, Kb, Vt, enc);
  transpose_ow<<<dim3(56, 64), 256, 0, stream>>>(ow, WoT);   // xb dead; reuse region
  gemm256<1><<<dim3(224), dim3(512), 0, stream>>>(enc, WoT, 4096, 3584, 14, out, nullptr, nullptr);
}

// Round 5
// 737.786 us; speedup vs baseline: 1.2519x; 1.0182x over previous
//
#include <hip/hip_runtime.h>
#include <stdint.h>

// B=2, T=2048, D=3584, N=16, KH=8, H=256, G=2, WINDOW=1024
// Inputs FLOAT32; compute bf16 MFMA; output FLOAT32.
// attn_mask unused: tril ∧ triu(1-W) ≡ t-1023 <= s <= t (diag always valid).

typedef short bf16x8 __attribute__((ext_vector_type(8)));   // 8 bf16 = 4 VGPRs
typedef float f32x4 __attribute__((ext_vector_type(4)));

#define MFMA16(a, b, c) __builtin_amdgcn_mfma_f32_16x16x32_bf16((a), (b), (c), 0, 0, 0)

__device__ __forceinline__ uint16_t f2bf(float f) {
  uint32_t u = __builtin_bit_cast(uint32_t, f);
  u += 0x7FFFu + ((u >> 16) & 1u);   // RNE
  return (uint16_t)(u >> 16);
}
__device__ __forceinline__ float bf2f(uint16_t u) {
  return __builtin_bit_cast(float, (uint32_t)u << 16);
}
// async global->LDS, 16B/lane; LDS dest must be wave-uniform base + lane*16.
__device__ __forceinline__ void async16(void* lds, const void* g) {
  __builtin_amdgcn_global_load_lds(
      (const __attribute__((address_space(1))) uint32_t*)g,
      (__attribute__((address_space(3))) uint32_t*)lds, 16, 0, 0);
}

// ---------------------------------------------------------------------------
// x f32 -> bf16 (row-major copy); 8 elems/thread
// ---------------------------------------------------------------------------
__global__ void convert_x(const float* __restrict__ x, uint16_t* __restrict__ xb) {
  size_t i = ((size_t)blockIdx.x * 256 + threadIdx.x) * 8;
  f32x4 a = *(const f32x4*)(x + i);
  f32x4 b = *(const f32x4*)(x + i + 4);
  bf16x8 r;
  r[0] = (short)f2bf(a[0]); r[1] = (short)f2bf(a[1]);
  r[2] = (short)f2bf(a[2]); r[3] = (short)f2bf(a[3]);
  r[4] = (short)f2bf(b[0]); r[5] = (short)f2bf(b[1]);
  r[6] = (short)f2bf(b[2]); r[7] = (short)f2bf(b[3]);
  *(bf16x8*)(xb + i) = r;
}

// ---------------------------------------------------------------------------
// Weight transposes (f32 in, bf16 out), B^T (n-major, k-contiguous) layout
// ---------------------------------------------------------------------------
__global__ void transpose_qkvw(const float* __restrict__ qw,
                               const float* __restrict__ kvw,
                               uint16_t* __restrict__ WqkvT) {
  __shared__ uint16_t tile[64][65];
  const int j0 = blockIdx.x * 64;
  const int d0 = blockIdx.y * 64;
  const int t = threadIdx.x;
  const int jl = t & 63;
  const int q4 = t >> 6;
  const int j = j0 + jl;
  const float* src;
  if (j0 < 4096) {
    src = qw + (size_t)(j >> 8) * 3584 * 256 + (j & 255);
  } else {
    int j2 = j - 4096;
    src = kvw + ((size_t)((j2 >> 11) * 8 + ((j2 >> 8) & 7)) * 3584) * 256 + (j2 & 255);
  }
#pragma unroll
  for (int r = 0; r < 16; ++r) {
    int dl = r * 4 + q4;
    tile[jl][dl] = f2bf(src[(size_t)(d0 + dl) * 256]);
  }
  __syncthreads();
#pragma unroll
  for (int r = 0; r < 16; ++r) {
    int jl2 = r * 4 + q4;
    WqkvT[(size_t)(j0 + jl2) * 3584 + d0 + jl] = tile[jl2][jl];
  }
}

// WoT[d][j] = o_w flat (4096 x 3584)[j][d], f32 -> bf16
__global__ void transpose_ow(const float* __restrict__ ow, uint16_t* __restrict__ WoT) {
  __shared__ uint16_t tile[64][65];
  const int d0 = blockIdx.x * 64;
  const int j0 = blockIdx.y * 64;
  const int t = threadIdx.x;
  const int c = t & 63;
  const int q4 = t >> 6;
#pragma unroll
  for (int r = 0; r < 16; ++r) {
    int jl = r * 4 + q4;
    tile[c][jl] = f2bf(ow[(size_t)(j0 + jl) * 3584 + d0 + c]);   // coalesced in d
  }
  __syncthreads();
#pragma unroll
  for (int r = 0; r < 16; ++r) {
    int dl = r * 4 + q4;
    WoT[(size_t)(d0 + dl) * 4096 + j0 + c] = tile[dl][c];        // coalesced in j
  }
}

// ---------------------------------------------------------------------------
// GEMM, 256x256 tile, BK=32, 4-slot LDS ring, ONE barrier per K-tile.
//   512 threads = 8 waves (2 M x 4 N); per-wave output 128x64 (acc[8][4]).
//   Iter t: vmcnt(8) [tile t landed for this wave] -> s_barrier [all waves]
//   -> sched_barrier -> issue 4 DMA into slot t+3 [safe: slot holds tile t-1,
//   whose reads finished before barrier(t)] -> read 12 frags -> 32 MFMA.
//   R4's 4-barriers/K-tile lockstep forced all 8 waves' 96 ds_read_b128 into
//   shared windows (LDS pipe is the binding resource: 96KB/tile @256B/cy vs
//   ~310cy MFMA -> 62% geometric ceiling); 1 barrier/tile lets the 2 waves
//   per SIMD de-phase (one reads while the other MFMAs).
// EPI 0: epilogue routes cols to Q / K / V^T bf16 buffers.
// EPI 1: epilogue stores f32 to Oq.
// ---------------------------------------------------------------------------
template <int EPI>
__global__ __launch_bounds__(512, 2) void gemm256(
    const uint16_t* __restrict__ A, const uint16_t* __restrict__ Bt,
    int Kd, int Nc, int nbx,
    void* __restrict__ Oqv, uint16_t* __restrict__ Ok, uint16_t* __restrict__ Ov) {
  __shared__ uint16_t lds[4 * 16384];   // 128 KiB

  const int tid = threadIdx.x;
  const int lane = tid & 63;
  const int quad = lane >> 4;
  const int l15 = lane & 15;
  const int wave = tid >> 6;
  const int wm = wave & 1;        // M half (128 rows)
  const int wn = wave >> 1;       // N quarter (64 cols)

  // T1: XCD-aware bijective swizzle (requires nwg % 8 == 0; 512 and 224 both ok)
  const int nwg = gridDim.x;
  const int chunk = nwg >> 3;
  const int wg = blockIdx.x;
  const int swz = (wg & 7) * chunk + (wg >> 3);
  const int by = swz / nbx;
  const int bx = swz - by * nbx;
  const int m0 = by * 256;
  const int n0 = bx * 256;

  f32x4 acc[8][4];
#pragma unroll
  for (int i = 0; i < 8; ++i)
#pragma unroll
    for (int j = 0; j < 4; ++j) acc[i][j] = f32x4{0.f, 0.f, 0.f, 0.f};

  // Staging source pointers (pre-swizzled global chunk; LDS dest stays linear)
  const int srow = tid >> 2;              // 0..127
  const int sck = tid & 3;                // 16B chunk within 64B row
  const int gck0 = sck ^ ((srow >> 1) & 3);          // rows 0..127 and 128..255
  const int gck1 = sck ^ (((srow + 128) >> 1) & 3);  // share (row>>1)&3 parity
  const uint16_t* gA0 = A + (size_t)(m0 + srow) * Kd + gck0 * 8;
  const uint16_t* gA1 = A + (size_t)(m0 + srow + 128) * Kd + gck1 * 8;
  const uint16_t* gB0 = Bt + (size_t)(n0 + srow) * Kd + gck0 * 8;
  const uint16_t* gB1 = Bt + (size_t)(n0 + srow + 128) * Kd + gck1 * 8;

  const int T = Kd >> 5;                  // K tiles (112 or 128, both >= 3)

  // Prologue: stage tiles 0,1,2 into slots 0,1,2 (12 loads/thread, in flight)
#pragma unroll
  for (int pt = 0; pt < 3; ++pt) {
    uint16_t* sd = lds + pt * 16384;
    const int kt = pt * 32;
    async16(sd + tid * 8, gA0 + kt);
    async16(sd + 4096 + tid * 8, gA1 + kt);
    async16(sd + 8192 + tid * 8, gB0 + kt);
    async16(sd + 12288 + tid * 8, gB1 + kt);
  }

  const int arow = wm * 128;
  const int brow = wn * 64;

  for (int t = 0; t < T; ++t) {
    const uint16_t* sA = lds + (t & 3) * 16384;
    const uint16_t* sB = sA + 8192;
    uint16_t* sd = lds + ((t + 3) & 3) * 16384;      // prefetch dest slot
    int ts = t + 3;
    if (ts >= T) ts = T - 1;                         // clamped re-stage; harmless
    const int ktS = ts * 32;

    // tile t landed (oldest 4 of <=12 outstanding); then all waves agree.
    asm volatile("s_waitcnt vmcnt(8)" ::: "memory");
    __builtin_amdgcn_s_barrier();
    __builtin_amdgcn_sched_barrier(0);

    // issue next prefetch (overwrites tile t-1's slot; reads done pre-barrier)
    async16(sd + tid * 8, gA0 + ktS);
    async16(sd + 4096 + tid * 8, gA1 + ktS);
    async16(sd + 8192 + tid * 8, gB0 + ktS);
    async16(sd + 12288 + tid * 8, gB1 + ktS);

    bf16x8 bfr[4], af[8];
#pragma unroll
    for (int fn = 0; fn < 4; ++fn) {
      const int r = brow + fn * 16 + l15;
      bfr[fn] = *(const bf16x8*)(sB + r * 32 + ((quad ^ ((r >> 1) & 3)) << 3));
    }
#pragma unroll
    for (int i = 0; i < 8; ++i) {
      const int r = arow + i * 16 + l15;
      af[i] = *(const bf16x8*)(sA + r * 32 + ((quad ^ ((r >> 1) & 3)) << 3));
    }
    __builtin_amdgcn_s_setprio(1);
#pragma unroll
    for (int i = 0; i < 8; ++i)
#pragma unroll
      for (int fn = 0; fn < 4; ++fn)
        acc[i][fn] = MFMA16(af[i], bfr[fn], acc[i][fn]);
    __builtin_amdgcn_s_setprio(0);
  }

  // Drain remaining LDS-DMA before wave exit (slots die with the workgroup).
  asm volatile("s_waitcnt vmcnt(0)" ::: "memory");

  // C layout per 16x16 frag: col = lane&15, row = quad*4 + reg (guide-verified)
  const int rowb = m0 + wm * 128;
  const int colb = n0 + wn * 64;
  if (EPI == 0) {
    if (n0 < 4096) {           // Q: (B*T, N*H)
      uint16_t* Oq = (uint16_t*)Oqv;
#pragma unroll
      for (int fm = 0; fm < 8; ++fm)
#pragma unroll
        for (int fn = 0; fn < 4; ++fn) {
          const int r0 = rowb + fm * 16 + quad * 4;
          const int c = colb + fn * 16 + l15;
#pragma unroll
          for (int reg = 0; reg < 4; ++reg)
            Oq[(size_t)(r0 + reg) * 4096 + c] = f2bf(acc[fm][fn][reg]);
        }
    } else if (n0 < 6144) {    // K: (B*T, KH*H)
#pragma unroll
      for (int fm = 0; fm < 8; ++fm)
#pragma unroll
        for (int fn = 0; fn < 4; ++fn) {
          const int r0 = rowb + fm * 16 + quad * 4;
          const int c = colb + fn * 16 + l15 - 4096;
#pragma unroll
          for (int reg = 0; reg < 4; ++reg)
            Ok[(size_t)(r0 + reg) * 2048 + c] = f2bf(acc[fm][fn][reg]);
        }
    } else {                   // V transposed: Vt[b][kvh][h][t]
#pragma unroll
      for (int fm = 0; fm < 8; ++fm)
#pragma unroll
        for (int fn = 0; fn < 4; ++fn) {
          const int r0 = rowb + fm * 16 + quad * 4;   // 4 consecutive t
          const int c2 = colb + fn * 16 + l15 - 6144;
          const int kvh = c2 >> 8, h = c2 & 255;
          const int bb = r0 >> 11, tt = r0 & 2047;
          ushort4 pk;
          pk.x = f2bf(acc[fm][fn][0]);
          pk.y = f2bf(acc[fm][fn][1]);
          pk.z = f2bf(acc[fm][fn][2]);
          pk.w = f2bf(acc[fm][fn][3]);
          *(ushort4*)(Ov + ((((size_t)bb * 8 + kvh) * 256 + h) * 2048 + tt)) = pk;
        }
    }
  } else {                     // f32 output
    float* Oq = (float*)Oqv;
#pragma unroll
    for (int fm = 0; fm < 8; ++fm)
#pragma unroll
      for (int fn = 0; fn < 4; ++fn) {
        const int r0 = rowb + fm * 16 + quad * 4;
        const int c = colb + fn * 16 + l15;
#pragma unroll
        for (int reg = 0; reg < 4; ++reg)
          Oq[(size_t)(r0 + reg) * Nc + c] = acc[fm][fn][reg];
      }
  }
}

// ---------------------------------------------------------------------------
// RoPE in place on Q (B,T,N,H) and K (B,T,KH,H) [bf16]; Q additionally * 0.0625
// ---------------------------------------------------------------------------
__global__ void rope_kernel(uint16_t* __restrict__ Qb, uint16_t* __restrict__ Kb,
                            const int* __restrict__ segpos) {
  const size_t QN = (size_t)2 * 2048 * 16 * 128;   // 8388608 Q pairs
  size_t idx = (size_t)blockIdx.x * 256 + threadIdx.x;
  uint16_t* buf;
  size_t base;
  int i, t, b;
  bool isQ = idx < QN;
  if (isQ) {
    i = (int)(idx & 127);
    int nn = (int)((idx >> 7) & 15);
    t = (int)((idx >> 11) & 2047);
    b = (int)(idx >> 22);
    base = ((size_t)((b * 2048 + t) * 16 + nn) << 8) + i;
    buf = Qb;
  } else {
    size_t x2 = idx - QN;
    i = (int)(x2 & 127);
    int kh = (int)((x2 >> 7) & 7);
    t = (int)((x2 >> 10) & 2047);
    b = (int)(x2 >> 21);
    base = ((size_t)((b * 2048 + t) * 8 + kh) << 8) + i;
    buf = Kb;
  }
  float pos = (float)segpos[b * 2048 + t];
  float inv = exp2f((float)i * (-13.287712379549449f / 128.f));  // 10000^(-i/128)
  float ang = pos * inv;
  float sn = sinf(ang), cs = cosf(ang);
  float x1 = bf2f(buf[base]);
  float x2v = bf2f(buf[base + 128]);
  float o1 = x1 * cs - x2v * sn;
  float o2 = x2v * cs + x1 * sn;
  if (isQ) { o1 *= 0.0625f; o2 *= 0.0625f; }
  buf[base] = f2bf(o1);
  buf[base + 128] = f2bf(o2);
}

// ---------------------------------------------------------------------------
// Flash attention v4 (verified R4): 64 q-rows/block, 512 threads = 8 waves
//   (4 row-groups x 2 heads). Double-buffered K AND V via LDS-DMA; one
//   __syncthreads per tile; defer-max; setprio. Unchanged this round.
// ---------------------------------------------------------------------------
__global__ __launch_bounds__(512, 2) void attn_kernel(
    const uint16_t* __restrict__ Qb, const uint16_t* __restrict__ Kb,
    const uint16_t* __restrict__ Vt, uint16_t* __restrict__ enc) {
  __shared__ uint16_t Ks[2][64 * 256];   // 2 x 32 KB
  __shared__ uint16_t Vs[2][256 * 64];   // 2 x 32 KB
  __shared__ uint16_t Ps[8 * 16 * 72];   // 18 KB per-wave P (16 x 64, stride 72)
  const int tid = threadIdx.x;
  const int lane = tid & 63;
  const int wave = tid >> 6;
  const int quad = lane >> 4;
  const int l15 = lane & 15;

  // XCD swizzle: 512 wgs; each XCD gets 64 consecutive swz = 2 (b,kvh) groups
  const int bid = blockIdx.x;
  const int swz = (bid & 7) * 64 + (bid >> 3);
  const int qt0 = (swz & 31) * 64;
  const int y = swz >> 5;          // 0..15
  const int b = y >> 3;
  const int kvh = y & 7;
  const int g = wave & 1;
  const int wr = (wave >> 1) * 16; // row group: 0,16,32,48
  const int n = kvh * 2 + g;

  f32x4 oacc[16];
#pragma unroll
  for (int ht = 0; ht < 16; ++ht) oacc[ht] = f32x4{0.f, 0.f, 0.f, 0.f};
  float mrow[4], lrow[4];
#pragma unroll
  for (int r = 0; r < 4; ++r) { mrow[r] = -50.f; lrow[r] = 0.f; }

  // Q hoisted to registers: rows qt0+wr+l15, head n, chunk quad + c*32
  const uint16_t* qptr =
      Qb + ((size_t)((b * 2048 + qt0 + wr + l15) * 16 + n) << 8) + quad * 8;
  bf16x8 q[8];
#pragma unroll
  for (int c = 0; c < 8; ++c) q[c] = *(const bf16x8*)(qptr + c * 32);

  // K staging: 4 issues, rows r*16 + (tid>>5), dest chunk tid&31,
  // source chunk (tid&31)^(row&15); row&15 == tid>>5 (r*16 doesn't affect).
  const int krw = tid >> 5;            // 0..15
  const uint16_t* kg0 = Kb + (size_t)b * 4194304 + kvh * 256 +
                        (size_t)krw * 2048 + (((tid & 31) ^ krw) << 3);
  // V staging: 4 issues, rows h = r*64 + (tid>>3), dest chunk tid&7,
  // source chunk (tid&7)^(h&7); h&7 == (tid>>3)&7.
  const int vrw = tid >> 3;            // 0..63
  const uint16_t* vg0 = Vt + ((size_t)(b * 8 + kvh) << 19) +
                        (size_t)vrw * 2048 + (((tid & 7) ^ (vrw & 7)) << 3);

  int lo = qt0 - 1023;
  if (lo < 0) lo = 0;
  const int s0_start = (lo >> 6) << 6;

  // Prologue: stage tile 0 into buffer 0
#pragma unroll
  for (int r = 0; r < 4; ++r)
    async16(&Ks[0][r * 4096 + tid * 8], kg0 + (size_t)(s0_start + r * 16) * 2048);
#pragma unroll
  for (int r = 0; r < 4; ++r)
    async16(&Vs[0][r * 4096 + tid * 8], vg0 + (size_t)r * 131072 + s0_start);
  __syncthreads();   // vmcnt(0)+barrier: tile 0 visible

  int cur = 0;
  for (int s0 = s0_start; s0 <= qt0; s0 += 64, cur ^= 1) {
    // ---- issue next tile's DMA (lands during this tile's compute) ----
    if (s0 + 64 <= qt0) {
      uint16_t* kd = Ks[cur ^ 1];
      uint16_t* vd = Vs[cur ^ 1];
#pragma unroll
      for (int r = 0; r < 4; ++r)
        async16(kd + r * 4096 + tid * 8, kg0 + (size_t)(s0 + 64 + r * 16) * 2048);
#pragma unroll
      for (int r = 0; r < 4; ++r)
        async16(vd + r * 4096 + tid * 8, vg0 + (size_t)r * 131072 + (s0 + 64));
    }
    const uint16_t* ksb = Ks[cur];
    const uint16_t* vsb = Vs[cur];

    // ---- QK^T ----
    f32x4 sac[4];
#pragma unroll
    for (int j = 0; j < 4; ++j) sac[j] = f32x4{0.f, 0.f, 0.f, 0.f};
    __builtin_amdgcn_s_setprio(1);
#pragma unroll
    for (int c = 0; c < 8; ++c) {
#pragma unroll
      for (int j = 0; j < 4; ++j) {
        // stored: Ks[row][cd] = K[row][cd ^ (row&15)]; row&15 == l15 here
        bf16x8 kf = *(const bf16x8*)(ksb + (j * 16 + l15) * 256 +
                                     (((c * 4 + quad) ^ l15) << 3));
        sac[j] = MFMA16(q[c], kf, sac[j]);
      }
    }
    __builtin_amdgcn_s_setprio(0);

    // ---- softmax (rows quad*4+reg), online, defer-max THR=8 ----
#pragma unroll
    for (int reg = 0; reg < 4; ++reg) {
      const int t = qt0 + wr + quad * 4 + reg;
      float pv[4];
      float mx = -1e30f;
#pragma unroll
      for (int j = 0; j < 4; ++j) {
        int s = s0 + j * 16 + l15;
        float v = sac[j][reg];
        float e = __expf(v * 0.04f);                 // e^{2v/50}
        float scv = 50.f - 100.f / (e + 1.f);        // 50*tanh(v/50)
        bool valid = (s <= t) && (s + 1024 > t);
        v = valid ? scv : -1e30f;
        pv[j] = v;
        mx = fmaxf(mx, v);
      }
      mx = fmaxf(mx, __shfl_xor(mx, 1));
      mx = fmaxf(mx, __shfl_xor(mx, 2));
      mx = fmaxf(mx, __shfl_xor(mx, 4));
      mx = fmaxf(mx, __shfl_xor(mx, 8));
      float mold = mrow[reg];
      if (!__all(mx <= mold + 8.f)) {               // T13: rescale only on growth
        float mnew = fmaxf(mold, mx);
        float alpha = __expf(mold - mnew);
        lrow[reg] *= alpha;
#pragma unroll
        for (int ht = 0; ht < 16; ++ht) oacc[ht][reg] *= alpha;
        mrow[reg] = mnew;
        mold = mnew;
      }
      float rs = 0.f;
#pragma unroll
      for (int j = 0; j < 4; ++j) {
        float p = __expf(pv[j] - mold);              // bounded by e^8
        pv[j] = p;
        rs += p;
      }
      rs += __shfl_xor(rs, 1);
      rs += __shfl_xor(rs, 2);
      rs += __shfl_xor(rs, 4);
      rs += __shfl_xor(rs, 8);
      lrow[reg] += rs;
      const int r = quad * 4 + reg;
#pragma unroll
      for (int j = 0; j < 4; ++j)
        Ps[wave * 1152 + r * 72 + j * 16 + l15] = f2bf(pv[j]);
    }

    // ---- PV: P from own wave's LDS region, V from swizzled LDS ----
#pragma unroll
    for (int c2 = 0; c2 < 2; ++c2) {
      const int lch = c2 * 4 + quad;
      bf16x8 pf = *(const bf16x8*)(Ps + wave * 1152 + l15 * 72 + lch * 8);
      __builtin_amdgcn_s_setprio(1);
#pragma unroll
      for (int ht = 0; ht < 16; ++ht) {
        // stored: Vs[h][cd] = V[h][cd ^ (h&7)]; h&7 == l15&7 here
        bf16x8 vf = *(const bf16x8*)(vsb + (ht * 16 + l15) * 64 +
                                     ((lch ^ (l15 & 7)) << 3));
        oacc[ht] = MFMA16(pf, vf, oacc[ht]);
      }
      __builtin_amdgcn_s_setprio(0);
    }
    __syncthreads();   // vmcnt(0)+barrier: next tile landed; all reads retired
  }

#pragma unroll
  for (int reg = 0; reg < 4; ++reg) {
    float li = 1.f / lrow[reg];
    const int t = qt0 + wr + quad * 4 + reg;
    size_t base = ((size_t)((b * 2048 + t) * 16 + n) << 8) + l15;
#pragma unroll
    for (int ht = 0; ht < 16; ++ht)
      enc[base + ht * 16] = f2bf(oacc[ht][reg] * li);
  }
}

// ---------------------------------------------------------------------------
extern "C" void kernel_launch(void* const* d_in, const int* in_sizes, int n_in,
                              void* d_out, int out_size, void* d_ws, size_t ws_size,
                              hipStream_t stream) {
  const float* x = (const float*)d_in[0];
  const int* segpos = (const int*)d_in[1];
  // d_in[2] = attn_mask — implied by window; unused
  const float* qw = (const float*)d_in[3];
  const float* kvw = (const float*)d_in[4];
  const float* ow = (const float*)d_in[5];
  float* out = (float*)d_out;

  uint16_t* ws = (uint16_t*)d_ws;
  uint16_t* WqkvT = ws;                              // 29,360,128 elems
  uint16_t* enc = ws;                                // aliases WqkvT (dead after gemm<0>)
  uint16_t* xb = ws + (size_t)29360128;              // 14,680,064 (aliases WoT; dead after gemm<0>)
  uint16_t* WoT = ws + (size_t)29360128;             // 14,680,064 (written after attn)
  uint16_t* Qb = ws + (size_t)44040192;              // 16,777,216
  uint16_t* Kb = ws + (size_t)60817408;              // 8,388,608
  uint16_t* Vt = ws + (size_t)69206016;              // 8,388,608  (total ~155 MB)

  convert_x<<<7168, 256, 0, stream>>>(x, xb);
  transpose_qkvw<<<dim3(128, 56), 256, 0, stream>>>(qw, kvw, WqkvT);
  // 256x256 tiles: QKV = (4096 x 8192) -> 16 x 32 = 512 wgs; O = (4096 x 3584) -> 16 x 14 = 224 wgs
  gemm256<0><<<dim3(512), dim3(512), 0, stream>>>(xb, WqkvT, 3584, 8192, 32, Qb, Kb, Vt);
  rope_kernel<<<49152, 256, 0, stream>>>(Qb, Kb, segpos);
  attn_kernel<<<dim3(512), dim3(512), 0, stream>>>(Qb, Kb, Vt, enc);
  transpose_ow<<<dim3(56, 64), 256, 0, stream>>>(ow, WoT);   // xb dead; reuse region
  gemm256<1><<<dim3(224), dim3(512), 0, stream>>>(enc, WoT, 4096, 3584, 14, out, nullptr, nullptr);
}